// Round 6
// baseline (5686.219 us; speedup 1.0000x reference)
//
#include <hip/hip_runtime.h>
#include <math.h>

// ---- model dims ----
// B=32, H=64, W=1024; D=256, T=128 (BT=4096), L=6, HEADS=8 (hd=32), E=8, TOPK=2, HID=1024, V=8000
// ZERO-WORKSPACE design: d_ws is never touched. All scratch lives inside d_out
// (32,768,001 floats) and is overwritten by the final head GEMM via race-free
// telescoping passes.
//
// R1: MoE weight pre-transpose + hidden-split (FETCH 77->~25MB).
// R2: conv2/3/4 as NHWC implicit GEMM (stem 11ms -> ~1.8ms), total 5.5ms.
// R3: 128x64/8x4 tile — NEUTRAL. R4/R5: 128x128/8x8 — NEUTRAL (VALUBusy 72%,
// VGPR=80 starved: 64 acc + 32 frag > 80 -> reg shuffling; 2 barriers/k-step with
// only 2 waves/SIMD -> bubbles).
// R6: launch_bounds(256,1) (occupancy is grid-capped at 2 blocks/CU anyway) +
// double-buffered LDS with register prefetch: 1 barrier/k-step, global-load
// latency hidden under the FMA phase via ILP.

__device__ __forceinline__ float gelu_f(float x) {
  return 0.5f * x * (1.0f + erff(x * 0.70710678118654752440f));
}

// conv1 NHWC: x [Bc,1,64,1024] -> c1 [Bc,32,512,64], k3 s2 p1, bias+GELU
__global__ __launch_bounds__(256) void conv1_kernel(const float* __restrict__ x,
    const float* __restrict__ w, const float* __restrict__ bias, float* __restrict__ out) {
  int o = blockIdx.x * 256 + threadIdx.x;
  int co = o & 63, wo = (o >> 6) & 511, ho = (o >> 15) & 31, b = o >> 20;
  float acc = bias[co];
  const float* xp = x + (size_t)b * 65536;
  const float* wp = w + co * 9;
  #pragma unroll
  for (int kh = 0; kh < 3; kh++) {
    int hi = ho * 2 - 1 + kh;
    if ((unsigned)hi < 64u) {
      const float* row = xp + hi * 1024;
      #pragma unroll
      for (int kw = 0; kw < 3; kw++) {
        int wi = wo * 2 - 1 + kw;
        if ((unsigned)wi < 1024u) acc += row[wi] * wp[kh * 3 + kw];
      }
    }
  }
  out[o] = gelu_f(acc);
}

// conv weight transpose: w [CO][CI][3][3] -> wt [tap][CI][CO] (coalesced writes)
__global__ __launch_bounds__(256) void tr_cw_kernel(const float* __restrict__ w,
    float* __restrict__ o, int CI, int CO) {
  int i = blockIdx.x * 256 + threadIdx.x;
  if (i >= 9 * CI * CO) return;
  int co = i % CO; int r = i / CO; int ci = r % CI; int tap = r / CI;
  o[i] = w[(co * CI + ci) * 9 + tap];
}

// implicit-GEMM conv, NHWC in/out, k3 p1 stride S, bias+GELU fused.
// Double-buffered LDS, register prefetch, 1 barrier per 16-k step.
// in [BT][HI][WI][CI], wt [9][CI][CO], out [BT][HO][WO][CO]
// grid: (CO/128, M/128); 128x128 tile, 8x8 per thread.
template <int CI, int HI, int WI, int CO, int HO, int WO, int S>
__global__ __launch_bounds__(256, 1) void convgemm_db_kernel(
    const float* __restrict__ in, const float* __restrict__ wt,
    const float* __restrict__ bias, float* __restrict__ out) {
  constexpr int CI16 = CI / 16;     // k-steps per tap
  constexpr int NS = 9 * CI16;      // total k-steps
  __shared__ float As[2][16][132];
  __shared__ float Ws[2][16][132];
  int tid = threadIdx.x;
  int tileN = blockIdx.x * 128, tileM = blockIdx.y * 128;
  int tx = tid & 15, ty = tid >> 4;
  int ar = tid >> 1, ak = (tid & 1) << 3;   // A-stage: row 0..127, k-half 0/8
  int wk = tid >> 4, wc = (tid & 15) << 3;  // W-stage: k-row 0..15, co-offset
  int m = tileM + ar;
  int wo = m % WO, ho = (m / WO) % HO, b = m / (WO * HO);
  float acc[8][8];
  #pragma unroll
  for (int i = 0; i < 8; i++)
    #pragma unroll
    for (int j = 0; j < 8; j++) acc[i][j] = 0.0f;

  // prologue: load k-step 0 (tap 0, c0 = 0)
  float4 a0 = {0.f, 0.f, 0.f, 0.f}, a1 = {0.f, 0.f, 0.f, 0.f};
  {
    int hi = ho * S - 1, wi = wo * S - 1;
    if (((unsigned)hi < (unsigned)HI) && ((unsigned)wi < (unsigned)WI)) {
      const float* ip = in + ((size_t)(b * HI + hi) * WI + wi) * CI + ak;
      a0 = *(const float4*)ip; a1 = *(const float4*)(ip + 4);
    }
  }
  const float* wp0 = wt + (size_t)wk * CO + tileN + wc;
  float4 w0 = *(const float4*)wp0;
  float4 w1 = *(const float4*)(wp0 + 4);
  As[0][ak + 0][ar] = a0.x; As[0][ak + 1][ar] = a0.y; As[0][ak + 2][ar] = a0.z; As[0][ak + 3][ar] = a0.w;
  As[0][ak + 4][ar] = a1.x; As[0][ak + 5][ar] = a1.y; As[0][ak + 6][ar] = a1.z; As[0][ak + 7][ar] = a1.w;
  *(float4*)&Ws[0][wk][wc] = w0;
  *(float4*)&Ws[0][wk][wc + 4] = w1;
  __syncthreads();

  for (int ks = 0; ks < NS; ks++) {
    int cb = ks & 1;
    bool pf = (ks + 1 < NS);
    float4 na0 = {0.f, 0.f, 0.f, 0.f}, na1 = {0.f, 0.f, 0.f, 0.f};
    float4 nw0, nw1;
    if (pf) {
      int ksn = ks + 1;
      int tap = ksn / CI16;
      int c0 = (ksn % CI16) << 4;
      int kh = tap / 3, kw = tap - kh * 3;
      int hi = ho * S - 1 + kh, wi = wo * S - 1 + kw;
      if (((unsigned)hi < (unsigned)HI) && ((unsigned)wi < (unsigned)WI)) {
        const float* ip = in + ((size_t)(b * HI + hi) * WI + wi) * CI + c0 + ak;
        na0 = *(const float4*)ip; na1 = *(const float4*)(ip + 4);
      }
      const float* wp = wt + (size_t)tap * CI * CO + (size_t)(c0 + wk) * CO + tileN + wc;
      nw0 = *(const float4*)wp; nw1 = *(const float4*)(wp + 4);
    }
    const float (*Ab)[132] = As[cb];
    const float (*Wb)[132] = Ws[cb];
    #pragma unroll
    for (int kk = 0; kk < 16; kk++) {
      float4 av0 = *(const float4*)&Ab[kk][ty << 2];
      float4 av1 = *(const float4*)&Ab[kk][(ty << 2) + 64];
      float4 wv0 = *(const float4*)&Wb[kk][tx << 2];
      float4 wv1 = *(const float4*)&Wb[kk][(tx << 2) + 64];
      float a[8] = {av0.x, av0.y, av0.z, av0.w, av1.x, av1.y, av1.z, av1.w};
      float w[8] = {wv0.x, wv0.y, wv0.z, wv0.w, wv1.x, wv1.y, wv1.z, wv1.w};
      #pragma unroll
      for (int i = 0; i < 8; i++)
        #pragma unroll
        for (int j = 0; j < 8; j++) acc[i][j] += a[i] * w[j];
    }
    if (pf) {
      int nb = cb ^ 1;
      As[nb][ak + 0][ar] = na0.x; As[nb][ak + 1][ar] = na0.y;
      As[nb][ak + 2][ar] = na0.z; As[nb][ak + 3][ar] = na0.w;
      As[nb][ak + 4][ar] = na1.x; As[nb][ak + 5][ar] = na1.y;
      As[nb][ak + 6][ar] = na1.z; As[nb][ak + 7][ar] = na1.w;
      *(float4*)&Ws[nb][wk][wc] = nw0;
      *(float4*)&Ws[nb][wk][wc + 4] = nw1;
      __syncthreads();
    }
  }
  #pragma unroll
  for (int ih = 0; ih < 2; ih++) {
    #pragma unroll
    for (int i = 0; i < 4; i++) {
      float* Crow = out + (size_t)(tileM + ih * 64 + (ty << 2) + i) * CO + tileN;
      #pragma unroll
      for (int jh = 0; jh < 2; jh++) {
        #pragma unroll
        for (int j = 0; j < 4; j++) {
          int col = jh * 64 + (tx << 2) + j;
          Crow[col] = gelu_f(acc[ih * 4 + i][jh * 4 + j] + bias[tileN + col]);
        }
      }
    }
  }
}

// generic 128x128 8x8 GEMM: C[m0..m1, N] = A[m,K] @ W[N,K]^T + bias[N]
// N-tiles guarded (N need not be multiple of 128); K % 16 == 0.
__global__ __launch_bounds__(256) void gemm8_kernel(const float* __restrict__ A,
    const float* __restrict__ W, const float* __restrict__ bias, float* __restrict__ C,
    int N, int K, int addTo, int m0, int m1) {
  __shared__ float As[16][132];
  __shared__ float Ws[16][132];
  int tid = threadIdx.x;
  int tileN = blockIdx.x * 128, tileM = m0 + blockIdx.y * 128;
  int tx = tid & 15, ty = tid >> 4;
  int ar = tid >> 1, ak = (tid & 1) << 3;
  float acc[8][8];
  #pragma unroll
  for (int i = 0; i < 8; i++)
    #pragma unroll
    for (int j = 0; j < 8; j++) acc[i][j] = 0.0f;
  int arow = tileM + ar; if (arow > m1 - 1) arow = m1 - 1;
  int wrow = tileN + ar; if (wrow > N - 1) wrow = N - 1;
  const float* Ap = A + (size_t)arow * K + ak;
  const float* Wp = W + (size_t)wrow * K + ak;
  for (int k0 = 0; k0 < K; k0 += 16) {
    float4 a0 = *(const float4*)(Ap + k0);
    float4 a1 = *(const float4*)(Ap + k0 + 4);
    float4 w0 = *(const float4*)(Wp + k0);
    float4 w1 = *(const float4*)(Wp + k0 + 4);
    As[ak + 0][ar] = a0.x; As[ak + 1][ar] = a0.y; As[ak + 2][ar] = a0.z; As[ak + 3][ar] = a0.w;
    As[ak + 4][ar] = a1.x; As[ak + 5][ar] = a1.y; As[ak + 6][ar] = a1.z; As[ak + 7][ar] = a1.w;
    Ws[ak + 0][ar] = w0.x; Ws[ak + 1][ar] = w0.y; Ws[ak + 2][ar] = w0.z; Ws[ak + 3][ar] = w0.w;
    Ws[ak + 4][ar] = w1.x; Ws[ak + 5][ar] = w1.y; Ws[ak + 6][ar] = w1.z; Ws[ak + 7][ar] = w1.w;
    __syncthreads();
    #pragma unroll
    for (int kk = 0; kk < 16; kk++) {
      float4 av0 = *(const float4*)&As[kk][ty << 2];
      float4 av1 = *(const float4*)&As[kk][(ty << 2) + 64];
      float4 wv0 = *(const float4*)&Ws[kk][tx << 2];
      float4 wv1 = *(const float4*)&Ws[kk][(tx << 2) + 64];
      float a[8] = {av0.x, av0.y, av0.z, av0.w, av1.x, av1.y, av1.z, av1.w};
      float w[8] = {wv0.x, wv0.y, wv0.z, wv0.w, wv1.x, wv1.y, wv1.z, wv1.w};
      #pragma unroll
      for (int i = 0; i < 8; i++)
        #pragma unroll
        for (int j = 0; j < 8; j++) acc[i][j] += a[i] * w[j];
    }
    __syncthreads();
  }
  #pragma unroll
  for (int ih = 0; ih < 2; ih++) {
    #pragma unroll
    for (int i = 0; i < 4; i++) {
      int m = tileM + ih * 64 + (ty << 2) + i;
      if (m < m1) {
        float* Crow = C + (size_t)m * N;
        #pragma unroll
        for (int jh = 0; jh < 2; jh++) {
          #pragma unroll
          for (int j = 0; j < 4; j++) {
            int col = tileN + jh * 64 + (tx << 2) + j;
            if (col < N) {
              float v = acc[ih * 4 + i][jh * 4 + j] + bias[col];
              if (addTo) Crow[col] += v; else Crow[col] = v;
            }
          }
        }
      }
    }
  }
}

// mean over H'(8) + pos-enc: c4 NHWC [32][8][128][256] -> h [(b*128+t)*256+d]
__global__ __launch_bounds__(256) void token_kernel(const float* __restrict__ f, float* __restrict__ h) {
  int i = blockIdx.x * 256 + threadIdx.x;   // [b][t][d], d fastest
  int d = i & 255, t = (i >> 8) & 127, b = i >> 15;
  const float* fp = f + ((size_t)(b * 8) * 128 + t) * 256 + d;
  float s = 0.0f;
  #pragma unroll
  for (int ho = 0; ho < 8; ho++) s += fp[(size_t)ho * 32768];
  float tok = s * 0.125f;
  int i2 = d & ~1;
  float freq = expf(-(float)i2 * (float)(9.210340371976184 / 256.0)); // ln(10000)/256
  float ang = (float)t * freq;
  float pe = (d & 1) ? cosf(ang) : sinf(ang);
  h[i] = tok + pe;
}

// LayerNorm over last dim (256); one wave per row
__global__ __launch_bounds__(64) void ln_kernel(const float* __restrict__ in, float* __restrict__ out,
    const float* __restrict__ g, const float* __restrict__ b) {
  int row = blockIdx.x;
  int lane = threadIdx.x;
  float4 v = ((const float4*)(in + (size_t)row * 256))[lane];
  float s = v.x + v.y + v.z + v.w;
  float s2 = v.x * v.x + v.y * v.y + v.z * v.z + v.w * v.w;
  #pragma unroll
  for (int m = 1; m < 64; m <<= 1) { s += __shfl_xor(s, m); s2 += __shfl_xor(s2, m); }
  float mean = s * (1.0f / 256.0f);
  float var = s2 * (1.0f / 256.0f) - mean * mean;
  float rstd = rsqrtf(var + 1e-5f);
  float4 gv = ((const float4*)g)[lane];
  float4 bv = ((const float4*)b)[lane];
  float4 ov;
  ov.x = (v.x - mean) * rstd * gv.x + bv.x;
  ov.y = (v.y - mean) * rstd * gv.y + bv.y;
  ov.z = (v.z - mean) * rstd * gv.z + bv.z;
  ov.w = (v.w - mean) * rstd * gv.w + bv.w;
  ((float4*)(out + (size_t)row * 256))[lane] = ov;
}

// 128x64-tile GEMM (R3), kept for the small layer GEMMs (qkv/proj)
__global__ __launch_bounds__(256) void gemm128_kernel(const float* __restrict__ A, const float* __restrict__ W,
    const float* __restrict__ bias, float* __restrict__ C, int N, int K, int addTo, int m0, int m1) {
  __shared__ float As[16][136];
  __shared__ float Ws[16][68];
  int tid = threadIdx.x;
  int tileN = blockIdx.x * 64, tileM = m0 + blockIdx.y * 128;
  int ar = tid >> 1, ak = (tid & 1) << 3;
  int wr = tid >> 2, wk = (tid & 3) << 2;
  int tx = tid & 15, ty = tid >> 4;
  float acc[8][4];
  #pragma unroll
  for (int i = 0; i < 8; i++)
    #pragma unroll
    for (int j = 0; j < 4; j++) acc[i][j] = 0.0f;
  int arow = tileM + ar; if (arow > m1 - 1) arow = m1 - 1;
  const float* Ap = A + (size_t)arow * K + ak;
  const float* Wp = W + (size_t)(tileN + wr) * K + wk;
  for (int k0 = 0; k0 < K; k0 += 16) {
    float4 a0 = *(const float4*)(Ap + k0);
    float4 a1 = *(const float4*)(Ap + k0 + 4);
    float4 w4 = *(const float4*)(Wp + k0);
    As[ak + 0][ar] = a0.x; As[ak + 1][ar] = a0.y; As[ak + 2][ar] = a0.z; As[ak + 3][ar] = a0.w;
    As[ak + 4][ar] = a1.x; As[ak + 5][ar] = a1.y; As[ak + 6][ar] = a1.z; As[ak + 7][ar] = a1.w;
    Ws[wk + 0][wr] = w4.x; Ws[wk + 1][wr] = w4.y; Ws[wk + 2][wr] = w4.z; Ws[wk + 3][wr] = w4.w;
    __syncthreads();
    #pragma unroll
    for (int kk = 0; kk < 16; kk++) {
      float4 av0 = *(const float4*)&As[kk][ty << 3];
      float4 av1 = *(const float4*)&As[kk][(ty << 3) + 4];
      float4 wv = *(const float4*)&Ws[kk][tx << 2];
      float a[8] = {av0.x, av0.y, av0.z, av0.w, av1.x, av1.y, av1.z, av1.w};
      float w[4] = {wv.x, wv.y, wv.z, wv.w};
      #pragma unroll
      for (int i = 0; i < 8; i++)
        #pragma unroll
        for (int j = 0; j < 4; j++) acc[i][j] += a[i] * w[j];
    }
    __syncthreads();
  }
  #pragma unroll
  for (int i = 0; i < 8; i++) {
    int m = tileM + (ty << 3) + i;
    if (m < m1) {
      float* Crow = C + (size_t)m * N + tileN + (tx << 2);
      #pragma unroll
      for (int j = 0; j < 4; j++) {
        float v = acc[i][j] + bias[tileN + (tx << 2) + j];
        if (addTo) Crow[j] += v; else Crow[j] = v;
      }
    }
  }
}

// legacy 64x64 GEMM, kept for the tiny telescoping passes
__global__ __launch_bounds__(256) void gemm_kernel(const float* __restrict__ A, const float* __restrict__ W,
    const float* __restrict__ bias, float* __restrict__ C, int N, int K, int addTo, int m0, int m1) {
  __shared__ float As[16][68];
  __shared__ float Ws[16][68];
  int tid = threadIdx.x;
  int tileN = blockIdx.x * 64, tileM = m0 + blockIdx.y * 64;
  int lr = tid >> 2, lk = (tid & 3) << 2;
  int tx = tid & 15, ty = tid >> 4;
  float acc[4][4];
  #pragma unroll
  for (int i = 0; i < 4; i++)
    #pragma unroll
    for (int j = 0; j < 4; j++) acc[i][j] = 0.0f;
  int arow = tileM + lr; if (arow > m1 - 1) arow = m1 - 1;
  const float* Ap = A + (size_t)arow * K + lk;
  const float* Wp = W + (size_t)(tileN + lr) * K + lk;
  for (int k0 = 0; k0 < K; k0 += 16) {
    float4 a4 = *(const float4*)(Ap + k0);
    float4 w4 = *(const float4*)(Wp + k0);
    As[lk + 0][lr] = a4.x; As[lk + 1][lr] = a4.y; As[lk + 2][lr] = a4.z; As[lk + 3][lr] = a4.w;
    Ws[lk + 0][lr] = w4.x; Ws[lk + 1][lr] = w4.y; Ws[lk + 2][lr] = w4.z; Ws[lk + 3][lr] = w4.w;
    __syncthreads();
    #pragma unroll
    for (int kk = 0; kk < 16; kk++) {
      float4 av = *(const float4*)&As[kk][ty << 2];
      float4 wv = *(const float4*)&Ws[kk][tx << 2];
      float a[4] = {av.x, av.y, av.z, av.w};
      float w[4] = {wv.x, wv.y, wv.z, wv.w};
      #pragma unroll
      for (int i = 0; i < 4; i++)
        #pragma unroll
        for (int j = 0; j < 4; j++) acc[i][j] += a[i] * w[j];
    }
    __syncthreads();
  }
  #pragma unroll
  for (int i = 0; i < 4; i++) {
    int m = tileM + (ty << 2) + i;
    if (m < m1) {
      float* Crow = C + (size_t)m * N + tileN + (tx << 2);
      #pragma unroll
      for (int j = 0; j < 4; j++) {
        float v = acc[i][j] + bias[tileN + (tx << 2) + j];
        if (addTo) Crow[j] += v; else Crow[j] = v;
      }
    }
  }
}

// head row 0: single block; stages y row 0 in LDS (y aliases out[0..256)), then writes out[0..8000)
__global__ __launch_bounds__(256) void head_row0_kernel(const float* __restrict__ y,
    const float* __restrict__ W, const float* __restrict__ bias, float* __restrict__ out) {
  __shared__ float yrow[256];
  int tid = threadIdx.x;
  yrow[tid] = y[tid];
  __syncthreads();
  for (int col = tid; col < 8000; col += 256) {
    const float4* wp = (const float4*)(W + (size_t)col * 256);
    float acc = 0.0f;
    for (int d = 0; d < 64; d++) {
      float4 w4 = wp[d];
      acc += w4.x * yrow[d * 4] + w4.y * yrow[d * 4 + 1] + w4.z * yrow[d * 4 + 2] + w4.w * yrow[d * 4 + 3];
    }
    out[col] = acc + bias[col];
  }
}

// attention: one block per (b,head), 128 threads (one query row each); two-pass softmax
__global__ __launch_bounds__(128) void attn_kernel(const float* __restrict__ qkv, float* __restrict__ o) {
  __shared__ float Ks[128][33];
  __shared__ float Vs[128][33];
  int b = blockIdx.x >> 3, hh = blockIdx.x & 7;
  int t = threadIdx.x;
  const float* base = qkv + (size_t)(b * 128 + t) * 768 + hh * 32;
  float q[32];
  #pragma unroll
  for (int i = 0; i < 32; i += 4) {
    float4 v4 = *(const float4*)(base + i);
    q[i] = v4.x; q[i + 1] = v4.y; q[i + 2] = v4.z; q[i + 3] = v4.w;
    float4 k4 = *(const float4*)(base + 256 + i);
    Ks[t][i] = k4.x; Ks[t][i + 1] = k4.y; Ks[t][i + 2] = k4.z; Ks[t][i + 3] = k4.w;
    float4 w4 = *(const float4*)(base + 512 + i);
    Vs[t][i] = w4.x; Vs[t][i + 1] = w4.y; Vs[t][i + 2] = w4.z; Vs[t][i + 3] = w4.w;
  }
  __syncthreads();
  const float scale = 0.17677669529663687f; // 1/sqrt(32)
  float m = -1e30f;
  for (int j = 0; j < 128; j++) {
    float s = 0.0f;
    #pragma unroll
    for (int i = 0; i < 32; i++) s += q[i] * Ks[j][i];
    m = fmaxf(m, s);
  }
  m *= scale;
  float l = 0.0f;
  float acc[32];
  #pragma unroll
  for (int i = 0; i < 32; i++) acc[i] = 0.0f;
  for (int j = 0; j < 128; j++) {
    float s = 0.0f;
    #pragma unroll
    for (int i = 0; i < 32; i++) s += q[i] * Ks[j][i];
    float p = __expf(s * scale - m);
    l += p;
    #pragma unroll
    for (int i = 0; i < 32; i++) acc[i] += p * Vs[j][i];
  }
  float inv = 1.0f / l;
  float* op = o + (size_t)(b * 128 + t) * 256 + hh * 32;
  #pragma unroll
  for (int i = 0; i < 32; i++) op[i] = acc[i] * inv;
}

// router: one thread per token; writes top-2 idx/gates, accumulates softmax sums for aux
__global__ __launch_bounds__(256) void router_kernel(const float* __restrict__ y,
    const float* __restrict__ rw, const float* __restrict__ rb,
    int* __restrict__ eidx, float* __restrict__ egate, float* __restrict__ imp) {
  int token = blockIdx.x * 256 + threadIdx.x;
  const float4* yp4 = (const float4*)(y + (size_t)token * 256);
  float logit[8];
  #pragma unroll
  for (int e = 0; e < 8; e++) {
    const float4* wp = (const float4*)(rw + e * 256);
    float acc = 0.0f;
    for (int d = 0; d < 64; d++) {
      float4 w4 = wp[d]; float4 v4 = yp4[d];
      acc += w4.x * v4.x + w4.y * v4.y + w4.z * v4.z + w4.w * v4.w;
    }
    logit[e] = acc + rb[e];
  }
  float mx = logit[0];
  #pragma unroll
  for (int e = 1; e < 8; e++) mx = fmaxf(mx, logit[e]);
  float p[8]; float sum = 0.0f;
  #pragma unroll
  for (int e = 0; e < 8; e++) { p[e] = __expf(logit[e] - mx); sum += p[e]; }
  float inv = 1.0f / sum;
  #pragma unroll
  for (int e = 0; e < 8; e++) {
    float pe = p[e] * inv;
    #pragma unroll
    for (int msk = 1; msk < 64; msk <<= 1) pe += __shfl_xor(pe, msk);
    if ((threadIdx.x & 63) == 0) atomicAdd(&imp[e], pe);
  }
  // top-2 (ties -> lower index, matches lax.top_k)
  float m0 = -1e30f, m1 = -1e30f; int i0 = 0, i1 = 0;
  #pragma unroll
  for (int e = 0; e < 8; e++) {
    if (logit[e] > m0) { m1 = m0; i1 = i0; m0 = logit[e]; i0 = e; }
    else if (logit[e] > m1) { m1 = logit[e]; i1 = e; }
  }
  float g1 = __expf(m1 - m0);
  float g0 = 1.0f / (1.0f + g1);
  g1 *= g0;
  eidx[token * 2] = i0; eidx[token * 2 + 1] = i1;
  egate[token * 2] = g0; egate[token * 2 + 1] = g1;
}

// weight pre-transpose for coalesced MoE loads:
// w1 [8][1024][256] -> w1t (float4) [(e*64 + d4)*1024 + r] = w1[e][r][4*d4 .. +3]
__global__ __launch_bounds__(256) void tr_w1_kernel(const float* __restrict__ w, float4* __restrict__ o) {
  int i = blockIdx.x * 256 + threadIdx.x;          // 524288 float4 outputs
  int r = i & 1023, d4 = (i >> 10) & 63, e = i >> 16;
  o[i] = *(const float4*)(w + ((size_t)(e * 1024 + r)) * 256 + (d4 << 2));
}
// w2 [8][256][1024] -> w2t (float4) [(e*256 + j4)*256 + dd] = w2[e][dd][4*j4 .. +3]
__global__ __launch_bounds__(256) void tr_w2_kernel(const float* __restrict__ w, float4* __restrict__ o) {
  int i = blockIdx.x * 256 + threadIdx.x;          // 524288 float4 outputs
  int dd = i & 255, j4 = (i >> 8) & 255, e = i >> 16;
  o[i] = *(const float4*)(w + ((size_t)(e * 256 + dd)) * 1024 + (j4 << 2));
}

// grouped MoE: block = (expert e, slot-chunk of 128, hidden-half jc).
__global__ __launch_bounds__(256) void moe_kernel(const float* __restrict__ y,
    const float4* __restrict__ w1t, const float* __restrict__ b1,
    const float4* __restrict__ w2t, const float* __restrict__ b2,
    const int* __restrict__ eidx, const float* __restrict__ egate,
    float* __restrict__ h) {
  __shared__ float4 ylds[16][64];
  __shared__ __align__(16) float hlds[16][512];
  __shared__ int list[128];
  __shared__ int cnt;
  int tid = threadIdx.x;
  int e = blockIdx.x >> 7;
  int c = (blockIdx.x >> 1) & 63;
  int jc = blockIdx.x & 1;
  if (tid == 0) cnt = 0;
  __syncthreads();
  if (tid < 128) {
    int s = c * 128 + tid;
    if (eidx[s] == e) list[atomicAdd(&cnt, 1)] = s;
  }
  __syncthreads();
  int n = cnt;
  if (n == 0) return;
  int g8 = tid >> 7;       // token half for phase2
  int dd = tid & 127;      // output dims dd and dd+128
  const float4* w1p = w1t + (size_t)e * 65536 + jc * 512 + tid;
  const float4* w2p = w2t + (size_t)e * 65536 + dd;
  float bb0 = b1[e * 1024 + jc * 512 + tid];
  float bb1 = b1[e * 1024 + jc * 512 + 256 + tid];
  float b2v0 = jc ? 0.0f : b2[e * 256 + dd];
  float b2v1 = jc ? 0.0f : b2[e * 256 + dd + 128];
  const float4* y4 = (const float4*)y;
  for (int base = 0; base < n; base += 16) {
    int nt = (n - base) < 16 ? (n - base) : 16;
    for (int idx = tid; idx < 16 * 64; idx += 256) {
      int ti = idx >> 6, d4 = idx & 63;
      int slot = list[base + (ti < nt ? ti : 0)];
      ylds[ti][d4] = y4[(size_t)(slot >> 1) * 64 + d4];
    }
    __syncthreads();
    float h0[16], h1[16];
    #pragma unroll
    for (int i = 0; i < 16; i++) { h0[i] = bb0; h1[i] = bb1; }
    for (int d4 = 0; d4 < 64; d4++) {
      float4 wa = w1p[(size_t)d4 * 1024];
      float4 wb = w1p[(size_t)d4 * 1024 + 256];
      #pragma unroll
      for (int i = 0; i < 16; i++) {
        float4 yv = ylds[i][d4];
        h0[i] += wa.x * yv.x + wa.y * yv.y + wa.z * yv.z + wa.w * yv.w;
        h1[i] += wb.x * yv.x + wb.y * yv.y + wb.z * yv.z + wb.w * yv.w;
      }
    }
    #pragma unroll
    for (int i = 0; i < 16; i++) {
      hlds[i][tid] = gelu_f(h0[i]);
      hlds[i][256 + tid] = gelu_f(h1[i]);
    }
    __syncthreads();
    float acc2a[8], acc2b[8];
    #pragma unroll
    for (int i = 0; i < 8; i++) { acc2a[i] = 0.0f; acc2b[i] = 0.0f; }
    for (int j4 = 0; j4 < 128; j4++) {
      float4 wa = w2p[(size_t)(jc * 128 + j4) * 256];
      float4 wb = w2p[(size_t)(jc * 128 + j4) * 256 + 128];
      #pragma unroll
      for (int i = 0; i < 8; i++) {
        float4 hv = *(const float4*)&hlds[g8 * 8 + i][j4 * 4];
        acc2a[i] += wa.x * hv.x + wa.y * hv.y + wa.z * hv.z + wa.w * hv.w;
        acc2b[i] += wb.x * hv.x + wb.y * hv.y + wb.z * hv.z + wb.w * hv.w;
      }
    }
    __syncthreads();
    #pragma unroll
    for (int i = 0; i < 8; i++) {
      int ii = g8 * 8 + i;
      if (ii < nt) {
        int slot = list[base + ii];
        float g = egate[slot];
        float* hp = h + (size_t)(slot >> 1) * 256;
        atomicAdd(hp + dd, g * (acc2a[i] + b2v0));
        atomicAdd(hp + dd + 128, g * (acc2b[i] + b2v1));
      }
    }
  }
}

__global__ void zero_kernel(float* __restrict__ p, int n) {
  int i = blockIdx.x * blockDim.x + threadIdx.x;
  if (i < n) p[i] = 0.0f;
}

__global__ void aux_kernel(const float* __restrict__ imp, float* __restrict__ out) {
  float total = 0.0f;
  for (int l = 0; l < 6; l++) {
    float a = 0.0f;
    for (int e = 0; e < 8; e++) {
      float v = imp[l * 8 + e] * (1.0f / 4096.0f) - 0.125f;
      a += v * v;
    }
    total += a * 0.125f;
  }
  out[0] = total * (1.0f / 6.0f);
}

extern "C" void kernel_launch(void* const* d_in, const int* in_sizes, int n_in,
                              void* d_out, int out_size, void* d_ws, size_t ws_size,
                              hipStream_t stream) {
  const float* x      = (const float*)d_in[0];
  const float* cw1    = (const float*)d_in[1];
  const float* cb1    = (const float*)d_in[2];
  const float* cw2    = (const float*)d_in[3];
  const float* cb2    = (const float*)d_in[4];
  const float* cw3    = (const float*)d_in[5];
  const float* cb3    = (const float*)d_in[6];
  const float* cw4    = (const float*)d_in[7];
  const float* cb4    = (const float*)d_in[8];
  const float* ln1_g  = (const float*)d_in[9];
  const float* ln1_b  = (const float*)d_in[10];
  const float* qkv_w  = (const float*)d_in[11];
  const float* qkv_b  = (const float*)d_in[12];
  const float* out_w  = (const float*)d_in[13];
  const float* out_b  = (const float*)d_in[14];
  const float* ln2_g  = (const float*)d_in[15];
  const float* ln2_b  = (const float*)d_in[16];
  const float* router_w = (const float*)d_in[17];
  const float* router_b = (const float*)d_in[18];
  const float* e_w1   = (const float*)d_in[19];
  const float* e_b1   = (const float*)d_in[20];
  const float* e_w2   = (const float*)d_in[21];
  const float* e_b2   = (const float*)d_in[22];
  const float* normf_g = (const float*)d_in[23];
  const float* normf_b = (const float*)d_in[24];
  const float* head_w = (const float*)d_in[25];
  const float* head_b = (const float*)d_in[26];
  float* out = (float*)d_out;
  (void)d_ws; (void)ws_size;  // deliberately unused

  // ---- arena inside d_out (floats); peak abs offset 28,221,440 < 32,768,001 ----
  float* y = out;                       // [0 .. 1,048,576)  final-LN output parked at base
  float* h = out + 1048576;             // [1,048,576 .. 2,097,152)
  float* S = out + 2097152;             // scratch arena
  // stem (NHWC), 4 chunks of 8 batches:
  float* c2 = S;                        // 16,777,216  [32][16][256][128]
  float* c1 = S + 16777216;             //  8,388,608  per-chunk [8][32][512][64]
  float* c3 = S + 16777216;             //  8,388,608  [32][8][128][256] (aliases dead c1)
  float* c4 = S;                        //  8,388,608  [32][8][128][256] (aliases dead c2)
  float* cw2t = S + 25165824;           //     73,728  [9][64][128]
  float* cw3t = S + 25239552;           //    294,912  [9][128][256]
  float* cw4t = S + 25534464;           //    589,824  [9][256][256]
  // layer loop:
  float* qkvb = S;                      // 3,145,728
  float* ob   = S + 3145728;            // 1,048,576
  float* y2   = S + 4194304;            // 1,048,576
  int*   eidx  = (int*)(S + 5242880);   // 8192 ints
  float* egate = S + 5242880 + 8192;    // 8192 floats
  float* imp   = S + 5242880 + 16384;   // 48 floats
  float* w1t   = S + 5767168;           // 2,097,152 (per-layer transposed w1)
  float* w2t   = S + 7864320;           // 2,097,152 (per-layer transposed w2)

  // conv weight transposes (once)
  tr_cw_kernel<<<(9 * 64 * 128 + 255) / 256, 256, 0, stream>>>(cw2, cw2t, 64, 128);
  tr_cw_kernel<<<(9 * 128 * 256 + 255) / 256, 256, 0, stream>>>(cw3, cw3t, 128, 256);
  tr_cw_kernel<<<(9 * 256 * 256 + 255) / 256, 256, 0, stream>>>(cw4, cw4t, 256, 256);

  // conv1+conv2 chunked over batch (4 x Bc=8); conv3/conv4/token whole-batch
  for (int c = 0; c < 4; c++) {
    const float* xc = x + (size_t)c * 8 * 65536;
    conv1_kernel<<<32768, 256, 0, stream>>>(xc, cw1, cb1, c1);
    convgemm_db_kernel<64, 32, 512, 128, 16, 256, 2>
        <<<dim3(1, 256), 256, 0, stream>>>(c1, cw2t, cb2, c2 + (size_t)c * 4194304);
  }
  convgemm_db_kernel<128, 16, 256, 256, 8, 128, 2>
      <<<dim3(2, 256), 256, 0, stream>>>(c2, cw3t, cb3, c3);
  convgemm_db_kernel<256, 8, 128, 256, 8, 128, 1>
      <<<dim3(2, 256), 256, 0, stream>>>(c3, cw4t, cb4, c4);
  token_kernel<<<4096, 256, 0, stream>>>(c4, h);
  zero_kernel<<<1, 64, 0, stream>>>(imp, 48);   // after stem: stem scratch overlapped imp

  for (int l = 0; l < 6; l++) {
    tr_w1_kernel<<<2048, 256, 0, stream>>>(e_w1 + (size_t)l * 8 * 1024 * 256, (float4*)w1t);
    tr_w2_kernel<<<2048, 256, 0, stream>>>(e_w2 + (size_t)l * 8 * 256 * 1024, (float4*)w2t);
    ln_kernel<<<4096, 64, 0, stream>>>(h, y, ln1_g + l * 256, ln1_b + l * 256);
    gemm128_kernel<<<dim3(12, 32), 256, 0, stream>>>(y, qkv_w + (size_t)l * 768 * 256, qkv_b + l * 768,
                                                     qkvb, 768, 256, 0, 0, 4096);
    attn_kernel<<<256, 128, 0, stream>>>(qkvb, ob);
    gemm128_kernel<<<dim3(4, 32), 256, 0, stream>>>(ob, out_w + (size_t)l * 256 * 256, out_b + l * 256,
                                                    h, 256, 256, 1, 0, 4096);
    ln_kernel<<<4096, 64, 0, stream>>>(h, y2, ln2_g + l * 256, ln2_b + l * 256);
    router_kernel<<<16, 256, 0, stream>>>(y2, router_w + l * 8 * 256, router_b + l * 8,
                                          eidx, egate, imp + l * 8);
    moe_kernel<<<1024, 256, 0, stream>>>(y2, (const float4*)w1t, e_b1 + l * 8 * 1024,
                                         (const float4*)w2t, e_b2 + l * 8 * 256,
                                         eidx, egate, h);
  }

  // final LN -> y at d_out[0..1M)
  ln_kernel<<<4096, 64, 0, stream>>>(h, y, normf_g, normf_b);
  // aux before head pass 1 (pass 1 overwrites imp's region)
  aux_kernel<<<1, 1, 0, stream>>>(imp, out + 32768000);

  // head GEMM, telescoping passes (all writes disjoint from remaining y reads):
  // pass 1: rows 132..4095  -> out[1,056,000 .. 32,768,000)
  gemm8_kernel<<<dim3(63, 31), 256, 0, stream>>>(y, head_w, head_b, out, 8000, 256, 0, 132, 4096);
  // pass 2: rows 5..131     -> out[40,000 .. 1,056,000)
  gemm8_kernel<<<dim3(63, 1), 256, 0, stream>>>(y, head_w, head_b, out, 8000, 256, 0, 5, 132);
  // pass 3: rows 1..4       -> out[8,000 .. 40,000)
  gemm_kernel<<<dim3(125, 1), 256, 0, stream>>>(y, head_w, head_b, out, 8000, 256, 0, 1, 5);
  // pass 4: row 0           -> out[0 .. 8,000), y row 0 staged in LDS first
  head_row0_kernel<<<1, 256, 0, stream>>>(y, head_w, head_b, out);
}

// Round 8
// 4589.059 us; speedup vs baseline: 1.2391x; 1.2391x over previous
//
#include <hip/hip_runtime.h>
#include <math.h>

// ---- model dims ----
// B=32, H=64, W=1024; D=256, T=128 (BT=4096), L=6, HEADS=8 (hd=32), E=8, TOPK=2, HID=1024, V=8000
// ZERO-WORKSPACE design: d_ws is never touched. All scratch lives inside d_out
// (32,768,001 floats) and is overwritten by the final head GEMM via race-free
// telescoping passes.
//
// R1: MoE weight pre-transpose + hidden-split. R2: conv2/3/4 NHWC implicit GEMM.
// R3-R5: fp32 tile variants plateau at 43% of fp32 VALU peak, MfmaUtil=0.
// R6: dbuf regression, reverted.
// R7: conv2/3/4 on MFMA (bf16x3 split). FAILED NaN: B-stage wrote only 8 of 16
// bf16 per thread -> uninitialized LDS k in [8,16)+[24,32) fed the MFMA B-operand.
// R8: fix = stage both 8-element halves of B (two uint4 per thread, like A-stage).

typedef __bf16 bf16x8 __attribute__((ext_vector_type(8)));
typedef float f32x4 __attribute__((ext_vector_type(4)));

__device__ __forceinline__ float gelu_f(float x) {
  return 0.5f * x * (1.0f + erff(x * 0.70710678118654752440f));
}

// conv1 NHWC: x [Bc,1,64,1024] -> c1 [Bc,32,512,64], k3 s2 p1, bias+GELU
__global__ __launch_bounds__(256) void conv1_kernel(const float* __restrict__ x,
    const float* __restrict__ w, const float* __restrict__ bias, float* __restrict__ out) {
  int o = blockIdx.x * 256 + threadIdx.x;
  int co = o & 63, wo = (o >> 6) & 511, ho = (o >> 15) & 31, b = o >> 20;
  float acc = bias[co];
  const float* xp = x + (size_t)b * 65536;
  const float* wp = w + co * 9;
  #pragma unroll
  for (int kh = 0; kh < 3; kh++) {
    int hi = ho * 2 - 1 + kh;
    if ((unsigned)hi < 64u) {
      const float* row = xp + hi * 1024;
      #pragma unroll
      for (int kw = 0; kw < 3; kw++) {
        int wi = wo * 2 - 1 + kw;
        if ((unsigned)wi < 1024u) acc += row[wi] * wp[kh * 3 + kw];
      }
    }
  }
  out[o] = gelu_f(acc);
}

// conv weight split+transpose: w [CO][CI][3][3] -> hi/lo bf16 [tap][CO][CI]
__global__ __launch_bounds__(256) void tr_cw_bf16_kernel(const float* __restrict__ w,
    __bf16* __restrict__ hi, __bf16* __restrict__ lo, int CI, int CO) {
  int i = blockIdx.x * 256 + threadIdx.x;
  if (i >= 9 * CI * CO) return;
  int ci = i % CI; int r = i / CI; int co = r % CO; int tap = r / CO;
  float x = w[(co * CI + ci) * 9 + tap];
  __bf16 h = (__bf16)x;
  __bf16 l = (__bf16)(x - (float)h);
  hi[i] = h; lo[i] = l;
}

// MFMA implicit-GEMM conv, NHWC in/out, k3 p1 stride S, bias+GELU fused. bf16x3.
// in [BT][HI][WI][CI] fp32, wthi/wtlo [9][CO][CI] bf16 (k-contiguous), out NHWC fp32.
// grid: (CO/128, M/128); 128x128 tile, BK=32, 4 waves (64x64 quadrant each).
template <int CI, int HI, int WI, int CO, int HO, int WO, int S>
__global__ __launch_bounds__(256) void convmfma_kernel(
    const float* __restrict__ in, const __bf16* __restrict__ wthi,
    const __bf16* __restrict__ wtlo, const float* __restrict__ bias,
    float* __restrict__ out) {
  // LDS: row stride 40 bf16 (32 k + 8 pad) -> even bank spread, 16B-aligned rows
  __shared__ __bf16 Ah[128 * 40], Al[128 * 40], Bh[128 * 40], Bl[128 * 40];
  int tid = threadIdx.x;
  int lane = tid & 63, wid = tid >> 6;
  int wr = (wid >> 1) << 6, wc = (wid & 1) << 6;  // wave quadrant offsets
  int lr = lane & 15;              // fragment row (A) / col (B)
  int lk = (lane >> 4) << 3;       // fragment k offset {0,8,16,24}
  int tileN = blockIdx.x * 128, tileM = blockIdx.y * 128;
  int tr = tid >> 1;               // staging row (A: m-row; B: co-col), 0..127
  int tk = (tid & 1) << 4;         // staging k half {0,16}
  int m = tileM + tr;
  int wo = m % WO, ho = (m / WO) % HO, b = m / (WO * HO);
  f32x4 acc[4][4];
  #pragma unroll
  for (int i = 0; i < 4; i++)
    #pragma unroll
    for (int j = 0; j < 4; j++) acc[i][j] = (f32x4){0.f, 0.f, 0.f, 0.f};

  for (int tap = 0; tap < 9; tap++) {
    int kh = tap / 3, kw = tap - kh * 3;
    int hi_ = ho * S - 1 + kh, wi_ = wo * S - 1 + kw;
    bool ok = ((unsigned)hi_ < (unsigned)HI) && ((unsigned)wi_ < (unsigned)WI);
    const float* ip = in + ((size_t)(b * HI + hi_) * WI + wi_) * CI + tk;
    const __bf16* wph = wthi + ((size_t)tap * CO + tileN + tr) * CI + tk;
    const __bf16* wpl = wtlo + ((size_t)tap * CO + tileN + tr) * CI + tk;
    for (int c0 = 0; c0 < CI; c0 += 32) {
      // ---- stage A (fp32 -> hi/lo bf16, 16 k per thread) ----
      float v[16];
      #pragma unroll
      for (int q = 0; q < 4; q++) {
        float4 t4 = ok ? *(const float4*)(ip + c0 + q * 4) : (float4){0.f, 0.f, 0.f, 0.f};
        v[q * 4 + 0] = t4.x; v[q * 4 + 1] = t4.y; v[q * 4 + 2] = t4.z; v[q * 4 + 3] = t4.w;
      }
      bf16x8 hv0, hv1, lv0, lv1;
      #pragma unroll
      for (int j = 0; j < 8; j++) {
        __bf16 h0 = (__bf16)v[j];       hv0[j] = h0;
        lv0[j] = (__bf16)(v[j] - (float)h0);
        __bf16 h1 = (__bf16)v[8 + j];   hv1[j] = h1;
        lv1[j] = (__bf16)(v[8 + j] - (float)h1);
      }
      *(bf16x8*)&Ah[tr * 40 + tk] = hv0;
      *(bf16x8*)&Ah[tr * 40 + tk + 8] = hv1;
      *(bf16x8*)&Al[tr * 40 + tk] = lv0;
      *(bf16x8*)&Al[tr * 40 + tk + 8] = lv1;
      // ---- stage B (bf16 copy, FULL 16 k per thread — R7 bug was only 8) ----
      *(uint4*)&Bh[tr * 40 + tk] = *(const uint4*)(wph + c0);
      *(uint4*)&Bh[tr * 40 + tk + 8] = *(const uint4*)(wph + c0 + 8);
      *(uint4*)&Bl[tr * 40 + tk] = *(const uint4*)(wpl + c0);
      *(uint4*)&Bl[tr * 40 + tk + 8] = *(const uint4*)(wpl + c0 + 8);
      __syncthreads();
      // ---- compute: 16 tiles x 3 mfma ----
      bf16x8 ah[4], al[4];
      #pragma unroll
      for (int mt = 0; mt < 4; mt++) {
        int r = wr + mt * 16 + lr;
        ah[mt] = *(const bf16x8*)&Ah[r * 40 + lk];
        al[mt] = *(const bf16x8*)&Al[r * 40 + lk];
      }
      #pragma unroll
      for (int nt = 0; nt < 4; nt++) {
        int cc = wc + nt * 16 + lr;
        bf16x8 bh = *(const bf16x8*)&Bh[cc * 40 + lk];
        bf16x8 bl = *(const bf16x8*)&Bl[cc * 40 + lk];
        #pragma unroll
        for (int mt = 0; mt < 4; mt++) {
          acc[mt][nt] = __builtin_amdgcn_mfma_f32_16x16x32_bf16(ah[mt], bh, acc[mt][nt], 0, 0, 0);
          acc[mt][nt] = __builtin_amdgcn_mfma_f32_16x16x32_bf16(al[mt], bh, acc[mt][nt], 0, 0, 0);
          acc[mt][nt] = __builtin_amdgcn_mfma_f32_16x16x32_bf16(ah[mt], bl, acc[mt][nt], 0, 0, 0);
        }
      }
      __syncthreads();
    }
  }
  // epilogue: D col=lane&15, row=4*(lane>>4)+reg
  int drow = (lane >> 4) << 2;
  #pragma unroll
  for (int mt = 0; mt < 4; mt++) {
    #pragma unroll
    for (int nt = 0; nt < 4; nt++) {
      int orow = tileM + wr + mt * 16 + drow;
      int ocol = tileN + wc + nt * 16 + lr;
      float bv = bias[ocol];
      #pragma unroll
      for (int r = 0; r < 4; r++)
        out[(size_t)(orow + r) * CO + ocol] = gelu_f(acc[mt][nt][r] + bv);
    }
  }
}

// generic 128x128 8x8 fp32 GEMM (head): C[m0..m1, N] = A @ W^T + bias
__global__ __launch_bounds__(256) void gemm8_kernel(const float* __restrict__ A,
    const float* __restrict__ W, const float* __restrict__ bias, float* __restrict__ C,
    int N, int K, int addTo, int m0, int m1) {
  __shared__ float As[16][132];
  __shared__ float Ws[16][132];
  int tid = threadIdx.x;
  int tileN = blockIdx.x * 128, tileM = m0 + blockIdx.y * 128;
  int tx = tid & 15, ty = tid >> 4;
  int ar = tid >> 1, ak = (tid & 1) << 3;
  float acc[8][8];
  #pragma unroll
  for (int i = 0; i < 8; i++)
    #pragma unroll
    for (int j = 0; j < 8; j++) acc[i][j] = 0.0f;
  int arow = tileM + ar; if (arow > m1 - 1) arow = m1 - 1;
  int wrow = tileN + ar; if (wrow > N - 1) wrow = N - 1;
  const float* Ap = A + (size_t)arow * K + ak;
  const float* Wp = W + (size_t)wrow * K + ak;
  for (int k0 = 0; k0 < K; k0 += 16) {
    float4 a0 = *(const float4*)(Ap + k0);
    float4 a1 = *(const float4*)(Ap + k0 + 4);
    float4 w0 = *(const float4*)(Wp + k0);
    float4 w1 = *(const float4*)(Wp + k0 + 4);
    As[ak + 0][ar] = a0.x; As[ak + 1][ar] = a0.y; As[ak + 2][ar] = a0.z; As[ak + 3][ar] = a0.w;
    As[ak + 4][ar] = a1.x; As[ak + 5][ar] = a1.y; As[ak + 6][ar] = a1.z; As[ak + 7][ar] = a1.w;
    Ws[ak + 0][ar] = w0.x; Ws[ak + 1][ar] = w0.y; Ws[ak + 2][ar] = w0.z; Ws[ak + 3][ar] = w0.w;
    Ws[ak + 4][ar] = w1.x; Ws[ak + 5][ar] = w1.y; Ws[ak + 6][ar] = w1.z; Ws[ak + 7][ar] = w1.w;
    __syncthreads();
    #pragma unroll
    for (int kk = 0; kk < 16; kk++) {
      float4 av0 = *(const float4*)&As[kk][ty << 2];
      float4 av1 = *(const float4*)&As[kk][(ty << 2) + 64];
      float4 wv0 = *(const float4*)&Ws[kk][tx << 2];
      float4 wv1 = *(const float4*)&Ws[kk][(tx << 2) + 64];
      float a[8] = {av0.x, av0.y, av0.z, av0.w, av1.x, av1.y, av1.z, av1.w};
      float w[8] = {wv0.x, wv0.y, wv0.z, wv0.w, wv1.x, wv1.y, wv1.z, wv1.w};
      #pragma unroll
      for (int i = 0; i < 8; i++)
        #pragma unroll
        for (int j = 0; j < 8; j++) acc[i][j] += a[i] * w[j];
    }
    __syncthreads();
  }
  #pragma unroll
  for (int ih = 0; ih < 2; ih++) {
    #pragma unroll
    for (int i = 0; i < 4; i++) {
      int m = tileM + ih * 64 + (ty << 2) + i;
      if (m < m1) {
        float* Crow = C + (size_t)m * N;
        #pragma unroll
        for (int jh = 0; jh < 2; jh++) {
          #pragma unroll
          for (int j = 0; j < 4; j++) {
            int col = tileN + jh * 64 + (tx << 2) + j;
            if (col < N) {
              float v = acc[ih * 4 + i][jh * 4 + j] + bias[col];
              if (addTo) Crow[col] += v; else Crow[col] = v;
            }
          }
        }
      }
    }
  }
}

// mean over H'(8) + pos-enc: c4 NHWC [32][8][128][256] -> h [(b*128+t)*256+d]
__global__ __launch_bounds__(256) void token_kernel(const float* __restrict__ f, float* __restrict__ h) {
  int i = blockIdx.x * 256 + threadIdx.x;   // [b][t][d], d fastest
  int d = i & 255, t = (i >> 8) & 127, b = i >> 15;
  const float* fp = f + ((size_t)(b * 8) * 128 + t) * 256 + d;
  float s = 0.0f;
  #pragma unroll
  for (int ho = 0; ho < 8; ho++) s += fp[(size_t)ho * 32768];
  float tok = s * 0.125f;
  int i2 = d & ~1;
  float freq = expf(-(float)i2 * (float)(9.210340371976184 / 256.0)); // ln(10000)/256
  float ang = (float)t * freq;
  float pe = (d & 1) ? cosf(ang) : sinf(ang);
  h[i] = tok + pe;
}

// LayerNorm over last dim (256); one wave per row
__global__ __launch_bounds__(64) void ln_kernel(const float* __restrict__ in, float* __restrict__ out,
    const float* __restrict__ g, const float* __restrict__ b) {
  int row = blockIdx.x;
  int lane = threadIdx.x;
  float4 v = ((const float4*)(in + (size_t)row * 256))[lane];
  float s = v.x + v.y + v.z + v.w;
  float s2 = v.x * v.x + v.y * v.y + v.z * v.z + v.w * v.w;
  #pragma unroll
  for (int m = 1; m < 64; m <<= 1) { s += __shfl_xor(s, m); s2 += __shfl_xor(s2, m); }
  float mean = s * (1.0f / 256.0f);
  float var = s2 * (1.0f / 256.0f) - mean * mean;
  float rstd = rsqrtf(var + 1e-5f);
  float4 gv = ((const float4*)g)[lane];
  float4 bv = ((const float4*)b)[lane];
  float4 ov;
  ov.x = (v.x - mean) * rstd * gv.x + bv.x;
  ov.y = (v.y - mean) * rstd * gv.y + bv.y;
  ov.z = (v.z - mean) * rstd * gv.z + bv.z;
  ov.w = (v.w - mean) * rstd * gv.w + bv.w;
  ((float4*)(out + (size_t)row * 256))[lane] = ov;
}

// 128x64-tile GEMM, kept for the small layer GEMMs (qkv/proj)
__global__ __launch_bounds__(256) void gemm128_kernel(const float* __restrict__ A, const float* __restrict__ W,
    const float* __restrict__ bias, float* __restrict__ C, int N, int K, int addTo, int m0, int m1) {
  __shared__ float As[16][136];
  __shared__ float Ws[16][68];
  int tid = threadIdx.x;
  int tileN = blockIdx.x * 64, tileM = m0 + blockIdx.y * 128;
  int ar = tid >> 1, ak = (tid & 1) << 3;
  int wr = tid >> 2, wk = (tid & 3) << 2;
  int tx = tid & 15, ty = tid >> 4;
  float acc[8][4];
  #pragma unroll
  for (int i = 0; i < 8; i++)
    #pragma unroll
    for (int j = 0; j < 4; j++) acc[i][j] = 0.0f;
  int arow = tileM + ar; if (arow > m1 - 1) arow = m1 - 1;
  const float* Ap = A + (size_t)arow * K + ak;
  const float* Wp = W + (size_t)(tileN + wr) * K + wk;
  for (int k0 = 0; k0 < K; k0 += 16) {
    float4 a0 = *(const float4*)(Ap + k0);
    float4 a1 = *(const float4*)(Ap + k0 + 4);
    float4 w4 = *(const float4*)(Wp + k0);
    As[ak + 0][ar] = a0.x; As[ak + 1][ar] = a0.y; As[ak + 2][ar] = a0.z; As[ak + 3][ar] = a0.w;
    As[ak + 4][ar] = a1.x; As[ak + 5][ar] = a1.y; As[ak + 6][ar] = a1.z; As[ak + 7][ar] = a1.w;
    Ws[wk + 0][wr] = w4.x; Ws[wk + 1][wr] = w4.y; Ws[wk + 2][wr] = w4.z; Ws[wk + 3][wr] = w4.w;
    __syncthreads();
    #pragma unroll
    for (int kk = 0; kk < 16; kk++) {
      float4 av0 = *(const float4*)&As[kk][ty << 3];
      float4 av1 = *(const float4*)&As[kk][(ty << 3) + 4];
      float4 wv = *(const float4*)&Ws[kk][tx << 2];
      float a[8] = {av0.x, av0.y, av0.z, av0.w, av1.x, av1.y, av1.z, av1.w};
      float w[4] = {wv.x, wv.y, wv.z, wv.w};
      #pragma unroll
      for (int i = 0; i < 8; i++)
        #pragma unroll
        for (int j = 0; j < 4; j++) acc[i][j] += a[i] * w[j];
    }
    __syncthreads();
  }
  #pragma unroll
  for (int i = 0; i < 8; i++) {
    int m = tileM + (ty << 3) + i;
    if (m < m1) {
      float* Crow = C + (size_t)m * N + tileN + (tx << 2);
      #pragma unroll
      for (int j = 0; j < 4; j++) {
        float v = acc[i][j] + bias[tileN + (tx << 2) + j];
        if (addTo) Crow[j] += v; else Crow[j] = v;
      }
    }
  }
}

// legacy 64x64 GEMM, kept for the tiny telescoping passes
__global__ __launch_bounds__(256) void gemm_kernel(const float* __restrict__ A, const float* __restrict__ W,
    const float* __restrict__ bias, float* __restrict__ C, int N, int K, int addTo, int m0, int m1) {
  __shared__ float As[16][68];
  __shared__ float Ws[16][68];
  int tid = threadIdx.x;
  int tileN = blockIdx.x * 64, tileM = m0 + blockIdx.y * 64;
  int lr = tid >> 2, lk = (tid & 3) << 2;
  int tx = tid & 15, ty = tid >> 4;
  float acc[4][4];
  #pragma unroll
  for (int i = 0; i < 4; i++)
    #pragma unroll
    for (int j = 0; j < 4; j++) acc[i][j] = 0.0f;
  int arow = tileM + lr; if (arow > m1 - 1) arow = m1 - 1;
  const float* Ap = A + (size_t)arow * K + lk;
  const float* Wp = W + (size_t)(tileN + lr) * K + lk;
  for (int k0 = 0; k0 < K; k0 += 16) {
    float4 a4 = *(const float4*)(Ap + k0);
    float4 w4 = *(const float4*)(Wp + k0);
    As[lk + 0][lr] = a4.x; As[lk + 1][lr] = a4.y; As[lk + 2][lr] = a4.z; As[lk + 3][lr] = a4.w;
    Ws[lk + 0][lr] = w4.x; Ws[lk + 1][lr] = w4.y; Ws[lk + 2][lr] = w4.z; Ws[lk + 3][lr] = w4.w;
    __syncthreads();
    #pragma unroll
    for (int kk = 0; kk < 16; kk++) {
      float4 av = *(const float4*)&As[kk][ty << 2];
      float4 wv = *(const float4*)&Ws[kk][tx << 2];
      float a[4] = {av.x, av.y, av.z, av.w};
      float w[4] = {wv.x, wv.y, wv.z, wv.w};
      #pragma unroll
      for (int i = 0; i < 4; i++)
        #pragma unroll
        for (int j = 0; j < 4; j++) acc[i][j] += a[i] * w[j];
    }
    __syncthreads();
  }
  #pragma unroll
  for (int i = 0; i < 4; i++) {
    int m = tileM + (ty << 2) + i;
    if (m < m1) {
      float* Crow = C + (size_t)m * N + tileN + (tx << 2);
      #pragma unroll
      for (int j = 0; j < 4; j++) {
        float v = acc[i][j] + bias[tileN + (tx << 2) + j];
        if (addTo) Crow[j] += v; else Crow[j] = v;
      }
    }
  }
}

// head row 0: single block; stages y row 0 in LDS (y aliases out[0..256)), then writes out[0..8000)
__global__ __launch_bounds__(256) void head_row0_kernel(const float* __restrict__ y,
    const float* __restrict__ W, const float* __restrict__ bias, float* __restrict__ out) {
  __shared__ float yrow[256];
  int tid = threadIdx.x;
  yrow[tid] = y[tid];
  __syncthreads();
  for (int col = tid; col < 8000; col += 256) {
    const float4* wp = (const float4*)(W + (size_t)col * 256);
    float acc = 0.0f;
    for (int d = 0; d < 64; d++) {
      float4 w4 = wp[d];
      acc += w4.x * yrow[d * 4] + w4.y * yrow[d * 4 + 1] + w4.z * yrow[d * 4 + 2] + w4.w * yrow[d * 4 + 3];
    }
    out[col] = acc + bias[col];
  }
}

// attention: one block per (b,head), 128 threads (one query row each); two-pass softmax
__global__ __launch_bounds__(128) void attn_kernel(const float* __restrict__ qkv, float* __restrict__ o) {
  __shared__ float Ks[128][33];
  __shared__ float Vs[128][33];
  int b = blockIdx.x >> 3, hh = blockIdx.x & 7;
  int t = threadIdx.x;
  const float* base = qkv + (size_t)(b * 128 + t) * 768 + hh * 32;
  float q[32];
  #pragma unroll
  for (int i = 0; i < 32; i += 4) {
    float4 v4 = *(const float4*)(base + i);
    q[i] = v4.x; q[i + 1] = v4.y; q[i + 2] = v4.z; q[i + 3] = v4.w;
    float4 k4 = *(const float4*)(base + 256 + i);
    Ks[t][i] = k4.x; Ks[t][i + 1] = k4.y; Ks[t][i + 2] = k4.z; Ks[t][i + 3] = k4.w;
    float4 w4 = *(const float4*)(base + 512 + i);
    Vs[t][i] = w4.x; Vs[t][i + 1] = w4.y; Vs[t][i + 2] = w4.z; Vs[t][i + 3] = w4.w;
  }
  __syncthreads();
  const float scale = 0.17677669529663687f; // 1/sqrt(32)
  float m = -1e30f;
  for (int j = 0; j < 128; j++) {
    float s = 0.0f;
    #pragma unroll
    for (int i = 0; i < 32; i++) s += q[i] * Ks[j][i];
    m = fmaxf(m, s);
  }
  m *= scale;
  float l = 0.0f;
  float acc[32];
  #pragma unroll
  for (int i = 0; i < 32; i++) acc[i] = 0.0f;
  for (int j = 0; j < 128; j++) {
    float s = 0.0f;
    #pragma unroll
    for (int i = 0; i < 32; i++) s += q[i] * Ks[j][i];
    float p = __expf(s * scale - m);
    l += p;
    #pragma unroll
    for (int i = 0; i < 32; i++) acc[i] += p * Vs[j][i];
  }
  float inv = 1.0f / l;
  float* op = o + (size_t)(b * 128 + t) * 256 + hh * 32;
  #pragma unroll
  for (int i = 0; i < 32; i++) op[i] = acc[i] * inv;
}

// router: one thread per token; writes top-2 idx/gates, accumulates softmax sums for aux
__global__ __launch_bounds__(256) void router_kernel(const float* __restrict__ y,
    const float* __restrict__ rw, const float* __restrict__ rb,
    int* __restrict__ eidx, float* __restrict__ egate, float* __restrict__ imp) {
  int token = blockIdx.x * 256 + threadIdx.x;
  const float4* yp4 = (const float4*)(y + (size_t)token * 256);
  float logit[8];
  #pragma unroll
  for (int e = 0; e < 8; e++) {
    const float4* wp = (const float4*)(rw + e * 256);
    float acc = 0.0f;
    for (int d = 0; d < 64; d++) {
      float4 w4 = wp[d]; float4 v4 = yp4[d];
      acc += w4.x * v4.x + w4.y * v4.y + w4.z * v4.z + w4.w * v4.w;
    }
    logit[e] = acc + rb[e];
  }
  float mx = logit[0];
  #pragma unroll
  for (int e = 1; e < 8; e++) mx = fmaxf(mx, logit[e]);
  float p[8]; float sum = 0.0f;
  #pragma unroll
  for (int e = 0; e < 8; e++) { p[e] = __expf(logit[e] - mx); sum += p[e]; }
  float inv = 1.0f / sum;
  #pragma unroll
  for (int e = 0; e < 8; e++) {
    float pe = p[e] * inv;
    #pragma unroll
    for (int msk = 1; msk < 64; msk <<= 1) pe += __shfl_xor(pe, msk);
    if ((threadIdx.x & 63) == 0) atomicAdd(&imp[e], pe);
  }
  // top-2 (ties -> lower index, matches lax.top_k)
  float m0 = -1e30f, m1 = -1e30f; int i0 = 0, i1 = 0;
  #pragma unroll
  for (int e = 0; e < 8; e++) {
    if (logit[e] > m0) { m1 = m0; i1 = i0; m0 = logit[e]; i0 = e; }
    else if (logit[e] > m1) { m1 = logit[e]; i1 = e; }
  }
  float g1 = __expf(m1 - m0);
  float g0 = 1.0f / (1.0f + g1);
  g1 *= g0;
  eidx[token * 2] = i0; eidx[token * 2 + 1] = i1;
  egate[token * 2] = g0; egate[token * 2 + 1] = g1;
}

// weight pre-transpose for coalesced MoE loads:
// w1 [8][1024][256] -> w1t (float4) [(e*64 + d4)*1024 + r] = w1[e][r][4*d4 .. +3]
__global__ __launch_bounds__(256) void tr_w1_kernel(const float* __restrict__ w, float4* __restrict__ o) {
  int i = blockIdx.x * 256 + threadIdx.x;          // 524288 float4 outputs
  int r = i & 1023, d4 = (i >> 10) & 63, e = i >> 16;
  o[i] = *(const float4*)(w + ((size_t)(e * 1024 + r)) * 256 + (d4 << 2));
}
// w2 [8][256][1024] -> w2t (float4) [(e*256 + j4)*256 + dd] = w2[e][dd][4*j4 .. +3]
__global__ __launch_bounds__(256) void tr_w2_kernel(const float* __restrict__ w, float4* __restrict__ o) {
  int i = blockIdx.x * 256 + threadIdx.x;          // 524288 float4 outputs
  int dd = i & 255, j4 = (i >> 8) & 255, e = i >> 16;
  o[i] = *(const float4*)(w + ((size_t)(e * 256 + dd)) * 1024 + (j4 << 2));
}

// grouped MoE: block = (expert e, slot-chunk of 128, hidden-half jc).
__global__ __launch_bounds__(256) void moe_kernel(const float* __restrict__ y,
    const float4* __restrict__ w1t, const float* __restrict__ b1,
    const float4* __restrict__ w2t, const float* __restrict__ b2,
    const int* __restrict__ eidx, const float* __restrict__ egate,
    float* __restrict__ h) {
  __shared__ float4 ylds[16][64];
  __shared__ __align__(16) float hlds[16][512];
  __shared__ int list[128];
  __shared__ int cnt;
  int tid = threadIdx.x;
  int e = blockIdx.x >> 7;
  int c = (blockIdx.x >> 1) & 63;
  int jc = blockIdx.x & 1;
  if (tid == 0) cnt = 0;
  __syncthreads();
  if (tid < 128) {
    int s = c * 128 + tid;
    if (eidx[s] == e) list[atomicAdd(&cnt, 1)] = s;
  }
  __syncthreads();
  int n = cnt;
  if (n == 0) return;
  int g8 = tid >> 7;       // token half for phase2
  int dd = tid & 127;      // output dims dd and dd+128
  const float4* w1p = w1t + (size_t)e * 65536 + jc * 512 + tid;
  const float4* w2p = w2t + (size_t)e * 65536 + dd;
  float bb0 = b1[e * 1024 + jc * 512 + tid];
  float bb1 = b1[e * 1024 + jc * 512 + 256 + tid];
  float b2v0 = jc ? 0.0f : b2[e * 256 + dd];
  float b2v1 = jc ? 0.0f : b2[e * 256 + dd + 128];
  const float4* y4 = (const float4*)y;
  for (int base = 0; base < n; base += 16) {
    int nt = (n - base) < 16 ? (n - base) : 16;
    for (int idx = tid; idx < 16 * 64; idx += 256) {
      int ti = idx >> 6, d4 = idx & 63;
      int slot = list[base + (ti < nt ? ti : 0)];
      ylds[ti][d4] = y4[(size_t)(slot >> 1) * 64 + d4];
    }
    __syncthreads();
    float h0[16], h1[16];
    #pragma unroll
    for (int i = 0; i < 16; i++) { h0[i] = bb0; h1[i] = bb1; }
    for (int d4 = 0; d4 < 64; d4++) {
      float4 wa = w1p[(size_t)d4 * 1024];
      float4 wb = w1p[(size_t)d4 * 1024 + 256];
      #pragma unroll
      for (int i = 0; i < 16; i++) {
        float4 yv = ylds[i][d4];
        h0[i] += wa.x * yv.x + wa.y * yv.y + wa.z * yv.z + wa.w * yv.w;
        h1[i] += wb.x * yv.x + wb.y * yv.y + wb.z * yv.z + wb.w * yv.w;
      }
    }
    #pragma unroll
    for (int i = 0; i < 16; i++) {
      hlds[i][tid] = gelu_f(h0[i]);
      hlds[i][256 + tid] = gelu_f(h1[i]);
    }
    __syncthreads();
    float acc2a[8], acc2b[8];
    #pragma unroll
    for (int i = 0; i < 8; i++) { acc2a[i] = 0.0f; acc2b[i] = 0.0f; }
    for (int j4 = 0; j4 < 128; j4++) {
      float4 wa = w2p[(size_t)(jc * 128 + j4) * 256];
      float4 wb = w2p[(size_t)(jc * 128 + j4) * 256 + 128];
      #pragma unroll
      for (int i = 0; i < 8; i++) {
        float4 hv = *(const float4*)&hlds[g8 * 8 + i][j4 * 4];
        acc2a[i] += wa.x * hv.x + wa.y * hv.y + wa.z * hv.z + wa.w * hv.w;
        acc2b[i] += wb.x * hv.x + wb.y * hv.y + wb.z * hv.z + wb.w * hv.w;
      }
    }
    __syncthreads();
    #pragma unroll
    for (int i = 0; i < 8; i++) {
      int ii = g8 * 8 + i;
      if (ii < nt) {
        int slot = list[base + ii];
        float g = egate[slot];
        float* hp = h + (size_t)(slot >> 1) * 256;
        atomicAdd(hp + dd, g * (acc2a[i] + b2v0));
        atomicAdd(hp + dd + 128, g * (acc2b[i] + b2v1));
      }
    }
  }
}

__global__ void zero_kernel(float* __restrict__ p, int n) {
  int i = blockIdx.x * blockDim.x + threadIdx.x;
  if (i < n) p[i] = 0.0f;
}

__global__ void aux_kernel(const float* __restrict__ imp, float* __restrict__ out) {
  float total = 0.0f;
  for (int l = 0; l < 6; l++) {
    float a = 0.0f;
    for (int e = 0; e < 8; e++) {
      float v = imp[l * 8 + e] * (1.0f / 4096.0f) - 0.125f;
      a += v * v;
    }
    total += a * 0.125f;
  }
  out[0] = total * (1.0f / 6.0f);
}

extern "C" void kernel_launch(void* const* d_in, const int* in_sizes, int n_in,
                              void* d_out, int out_size, void* d_ws, size_t ws_size,
                              hipStream_t stream) {
  const float* x      = (const float*)d_in[0];
  const float* cw1    = (const float*)d_in[1];
  const float* cb1    = (const float*)d_in[2];
  const float* cw2    = (const float*)d_in[3];
  const float* cb2    = (const float*)d_in[4];
  const float* cw3    = (const float*)d_in[5];
  const float* cb3    = (const float*)d_in[6];
  const float* cw4    = (const float*)d_in[7];
  const float* cb4    = (const float*)d_in[8];
  const float* ln1_g  = (const float*)d_in[9];
  const float* ln1_b  = (const float*)d_in[10];
  const float* qkv_w  = (const float*)d_in[11];
  const float* qkv_b  = (const float*)d_in[12];
  const float* out_w  = (const float*)d_in[13];
  const float* out_b  = (const float*)d_in[14];
  const float* ln2_g  = (const float*)d_in[15];
  const float* ln2_b  = (const float*)d_in[16];
  const float* router_w = (const float*)d_in[17];
  const float* router_b = (const float*)d_in[18];
  const float* e_w1   = (const float*)d_in[19];
  const float* e_b1   = (const float*)d_in[20];
  const float* e_w2   = (const float*)d_in[21];
  const float* e_b2   = (const float*)d_in[22];
  const float* normf_g = (const float*)d_in[23];
  const float* normf_b = (const float*)d_in[24];
  const float* head_w = (const float*)d_in[25];
  const float* head_b = (const float*)d_in[26];
  float* out = (float*)d_out;
  (void)d_ws; (void)ws_size;  // deliberately unused

  // ---- arena inside d_out (floats); peak abs offset 28,221,440 < 32,768,001 ----
  float* y = out;                       // [0 .. 1,048,576)  final-LN output parked at base
  float* h = out + 1048576;             // [1,048,576 .. 2,097,152)
  float* S = out + 2097152;             // scratch arena
  // stem (NHWC), 4 chunks of 8 batches:
  float* c2 = S;                        // 16,777,216  [32][16][256][128]
  float* c1 = S + 16777216;             //  8,388,608  per-chunk [8][32][512][64]
  float* c3 = S + 16777216;             //  8,388,608  [32][8][128][256] (aliases dead c1)
  float* c4 = S;                        //  8,388,608  [32][8][128][256] (aliases dead c2)
  // conv weights, bf16 hi/lo, [tap][CO][CI] (ushort counts = 2x float slots)
  __bf16* cw2h = (__bf16*)(S + 25165824);   //  73,728 ush (36,864 fl)
  __bf16* cw2l = (__bf16*)(S + 25202688);
  __bf16* cw3h = (__bf16*)(S + 25239552);   // 294,912 ush (147,456 fl)
  __bf16* cw3l = (__bf16*)(S + 25387008);
  __bf16* cw4h = (__bf16*)(S + 25534464);   // 589,824 ush (294,912 fl)
  __bf16* cw4l = (__bf16*)(S + 25829376);   // ends 26,124,288
  // layer loop:
  float* qkvb = S;                      // 3,145,728
  float* ob   = S + 3145728;            // 1,048,576
  float* y2   = S + 4194304;            // 1,048,576
  int*   eidx  = (int*)(S + 5242880);   // 8192 ints
  float* egate = S + 5242880 + 8192;    // 8192 floats
  float* imp   = S + 5242880 + 16384;   // 48 floats
  float* w1t   = S + 5767168;           // 2,097,152 (per-layer transposed w1)
  float* w2t   = S + 7864320;           // 2,097,152 (per-layer transposed w2)

  // conv weight bf16 split+transpose (once)
  tr_cw_bf16_kernel<<<(9 * 64 * 128 + 255) / 256, 256, 0, stream>>>(cw2, cw2h, cw2l, 64, 128);
  tr_cw_bf16_kernel<<<(9 * 128 * 256 + 255) / 256, 256, 0, stream>>>(cw3, cw3h, cw3l, 128, 256);
  tr_cw_bf16_kernel<<<(9 * 256 * 256 + 255) / 256, 256, 0, stream>>>(cw4, cw4h, cw4l, 256, 256);

  // conv1+conv2 chunked over batch (4 x Bc=8); conv3/conv4/token whole-batch
  for (int c = 0; c < 4; c++) {
    const float* xc = x + (size_t)c * 8 * 65536;
    conv1_kernel<<<32768, 256, 0, stream>>>(xc, cw1, cb1, c1);
    convmfma_kernel<64, 32, 512, 128, 16, 256, 2>
        <<<dim3(1, 256), 256, 0, stream>>>(c1, cw2h, cw2l, cb2, c2 + (size_t)c * 4194304);
  }
  convmfma_kernel<128, 16, 256, 256, 8, 128, 2>
      <<<dim3(2, 256), 256, 0, stream>>>(c2, cw3h, cw3l, cb3, c3);
  convmfma_kernel<256, 8, 128, 256, 8, 128, 1>
      <<<dim3(2, 256), 256, 0, stream>>>(c3, cw4h, cw4l, cb4, c4);
  token_kernel<<<4096, 256, 0, stream>>>(c4, h);
  zero_kernel<<<1, 64, 0, stream>>>(imp, 48);   // after stem: stem scratch overlapped imp

  for (int l = 0; l < 6; l++) {
    tr_w1_kernel<<<2048, 256, 0, stream>>>(e_w1 + (size_t)l * 8 * 1024 * 256, (float4*)w1t);
    tr_w2_kernel<<<2048, 256, 0, stream>>>(e_w2 + (size_t)l * 8 * 256 * 1024, (float4*)w2t);
    ln_kernel<<<4096, 64, 0, stream>>>(h, y, ln1_g + l * 256, ln1_b + l * 256);
    gemm128_kernel<<<dim3(12, 32), 256, 0, stream>>>(y, qkv_w + (size_t)l * 768 * 256, qkv_b + l * 768,
                                                     qkvb, 768, 256, 0, 0, 4096);
    attn_kernel<<<256, 128, 0, stream>>>(qkvb, ob);
    gemm128_kernel<<<dim3(4, 32), 256, 0, stream>>>(ob, out_w + (size_t)l * 256 * 256, out_b + l * 256,
                                                    h, 256, 256, 1, 0, 4096);
    ln_kernel<<<4096, 64, 0, stream>>>(h, y2, ln2_g + l * 256, ln2_b + l * 256);
    router_kernel<<<16, 256, 0, stream>>>(y2, router_w + l * 8 * 256, router_b + l * 8,
                                          eidx, egate, imp + l * 8);
    moe_kernel<<<1024, 256, 0, stream>>>(y2, (const float4*)w1t, e_b1 + l * 8 * 1024,
                                         (const float4*)w2t, e_b2 + l * 8 * 256,
                                         eidx, egate, h);
  }

  // final LN -> y at d_out[0..1M)
  ln_kernel<<<4096, 64, 0, stream>>>(h, y, normf_g, normf_b);
  // aux before head pass 1 (pass 1 overwrites imp's region)
  aux_kernel<<<1, 1, 0, stream>>>(imp, out + 32768000);

  // head GEMM, telescoping passes (all writes disjoint from remaining y reads):
  // pass 1: rows 132..4095  -> out[1,056,000 .. 32,768,000)
  gemm8_kernel<<<dim3(63, 31), 256, 0, stream>>>(y, head_w, head_b, out, 8000, 256, 0, 132, 4096);
  // pass 2: rows 5..131     -> out[40,000 .. 1,056,000)
  gemm8_kernel<<<dim3(63, 1), 256, 0, stream>>>(y, head_w, head_b, out, 8000, 256, 0, 5, 132);
  // pass 3: rows 1..4       -> out[8,000 .. 40,000)
  gemm_kernel<<<dim3(125, 1), 256, 0, stream>>>(y, head_w, head_b, out, 8000, 256, 0, 1, 5);
  // pass 4: row 0           -> out[0 .. 8,000), y row 0 staged in LDS first
  head_row0_kernel<<<1, 256, 0, stream>>>(y, head_w, head_b, out);
}